// Round 2
// baseline (327.462 us; speedup 1.0000x reference)
//
#include <hip/hip_runtime.h>
#include <math.h>

#define NSEG 1024
#define DD 64
#define HH 32

// Kernel 1: segment start offsets via binary search (batch is sorted, int32).
__global__ void seg_off_kernel(const int* __restrict__ batch, int n, int* __restrict__ off) {
    int t = blockIdx.x * blockDim.x + threadIdx.x;
    if (t > NSEG) return;
    int lo = 0, hi = n;
    while (lo < hi) {
        int mid = (lo + hi) >> 1;
        if (batch[mid] < t) lo = mid + 1; else hi = mid;
    }
    off[t] = lo;   // off[1024] == n
}

// Main kernel: one block per segment, 4 waves, one node per wave per iter.
// lane -> (h = lane&31, dh = lane>>5): head h, d-half dh.
// Online softmax state (m,s) per head + accumulator A[h][dh*32+j].
// x rows are read directly from global (wave-broadcast of 2 cache lines; L1
// serves it) — no LDS staging, no inline-asm pipeline.
__launch_bounds__(256, 3)
__global__ void gattp_kernel(const float* __restrict__ x,
                             const float* __restrict__ Wg,
                             const float* __restrict__ bg,
                             const int* __restrict__ off,
                             float* __restrict__ out) {
    const int seg  = blockIdx.x;
    const int tid  = threadIdx.x;
    const int wave = tid >> 6;
    const int lane = tid & 63;
    const int h    = lane & 31;
    const int dh   = lane >> 5;

    __shared__ float lds_m[4][HH];
    __shared__ float lds_s[4][HH];
    __shared__ __align__(16) float lds_A[4][HH][DD + 1];  // pad 65 -> conflict-free
    __shared__ __align__(16) float Pbuf[HH][DD + 1];      // dedicated, no aliasing

    const int start = off[seg];
    const int end   = off[seg + 1];

    if (start >= end) {                 // empty segment -> relu(0) = 0
        if (tid < DD) out[seg * DD + tid] = 0.0f;
        return;
    }

    // Wg column half for this lane's head: wgc[j] = Wg[dh*32+j][h]
    float wgc[32];
#pragma unroll
    for (int j = 0; j < 32; ++j)
        wgc[j] = Wg[(dh * 32 + j) * HH + h];
    const float bgh = bg[h];

    float m = -INFINITY;
    float s = 0.0f;
    float A[32];
#pragma unroll
    for (int j = 0; j < 32; ++j) A[j] = 0.0f;

    for (int n = start + wave; n < end; n += 4) {
        const float* xp = x + (size_t)n * DD + dh * 32;
        float xr[32];
#pragma unroll
        for (int j = 0; j < 8; ++j) {
            float4 q = *reinterpret_cast<const float4*>(xp + j * 4);
            xr[j * 4]     = q.x;
            xr[j * 4 + 1] = q.y;
            xr[j * 4 + 2] = q.z;
            xr[j * 4 + 3] = q.w;
        }

        // gate: partial dot over this half, combine halves, add bias ONCE.
        float gs = 0.0f;
#pragma unroll
        for (int j = 0; j < 32; ++j) gs = fmaf(xr[j], wgc[j], gs);
        gs += __shfl_xor(gs, 32, 64);    // a+b == b+a exactly -> both dh lanes identical
        float g = gs + bgh;

        // online softmax update
        float mo = m;
        m = fmaxf(m, g);
        float r = __expf(mo - m);        // 0 on first node (mo=-inf), 1 if no update
        float a = __expf(g - m);
        s = fmaf(s, r, a);
        if (__any(mo < m)) {             // rescale only when some lane updated (r==1 otherwise)
#pragma unroll
            for (int j = 0; j < 32; ++j) A[j] *= r;
        }
#pragma unroll
        for (int j = 0; j < 32; ++j) A[j] = fmaf(a, xr[j], A[j]);
    }

    // dump per-wave state (both dh lanes write identical m/s; benign)
    lds_m[wave][h] = m;
    lds_s[wave][h] = s;
#pragma unroll
    for (int j = 0; j < 32; ++j) lds_A[wave][h][dh * 32 + j] = A[j];
    __syncthreads();

    if (wave == 0) {
        // merge the 4 wave copies per head
        float m0 = lds_m[0][h], m1 = lds_m[1][h], m2 = lds_m[2][h], m3 = lds_m[3][h];
        float M  = fmaxf(fmaxf(m0, m1), fmaxf(m2, m3));
        float w0 = __expf(m0 - M), w1 = __expf(m1 - M);
        float w2 = __expf(m2 - M), w3 = __expf(m3 - M);
        float stot = lds_s[0][h] * w0 + lds_s[1][h] * w1 +
                     lds_s[2][h] * w2 + lds_s[3][h] * w3;
        float c = 1.0f / (32.0f * stot);
#pragma unroll
        for (int j = 0; j < 32; ++j) {
            int d = dh * 32 + j;
            float v = (lds_A[0][h][d] * w0 + lds_A[1][h][d] * w1 +
                       lds_A[2][h][d] * w2 + lds_A[3][h][d] * w3) * c;
            Pbuf[h][d] = v;
        }
        asm volatile("s_waitcnt lgkmcnt(0)" ::: "memory");
        // cross-head sum: lane l owns output dim l. Pbuf stride 65 -> 2-way max.
        float acc = 0.0f;
#pragma unroll
        for (int hh = 0; hh < HH; ++hh) acc += Pbuf[hh][lane];
        out[seg * DD + lane] = fmaxf(acc, 0.0f);
    }
}

extern "C" void kernel_launch(void* const* d_in, const int* in_sizes, int n_in,
                              void* d_out, int out_size, void* d_ws, size_t ws_size,
                              hipStream_t stream) {
    const float* x     = (const float*)d_in[0];
    const int*   batch = (const int*)d_in[1];
    const float* Wg    = (const float*)d_in[2];
    const float* bg    = (const float*)d_in[3];
    float* out = (float*)d_out;
    const int N = in_sizes[1];          // 1,000,000 nodes
    int* off = (int*)d_ws;              // NSEG+1 ints

    seg_off_kernel<<<(NSEG + 1 + 255) / 256, 256, 0, stream>>>(batch, N, off);
    gattp_kernel<<<NSEG, 256, 0, stream>>>(x, Wg, bg, off, out);
}